// Round 2
// baseline (302.607 us; speedup 1.0000x reference)
//
#include <hip/hip_runtime.h>

// TileWarping: B=4, C=16, H=512, W=960, UP=4 -> out [4, 48, 128, 240] f32.
// R3 design: barrier-free direct gather + full per-thread load batching.
//  - R2 post-mortem: direct gather kept HBM traffic at compulsory (~134 MB,
//    cache absorbs the 4x tap amplification) but __launch_bounds__(320,8)
//    capped VGPRs at 32 -> only ~5-8 loads in flight per wave -> each wave
//    serialized 16 latency-bound load/compute batches (VALUBusy 10.7%,
//    dur 128us vs ~26us HBM-share floor).
//  - R3: issue ALL 80 loads (4 taps + 1 fea_l per channel, 16 channels)
//    into register arrays with static indexing BEFORE any compute.
//    launch_bounds(320,4) raises the VGPR cap to 128 (~100 used).
//    3 blocks/CU = 15 waves, each with up to 63 outstanding VMEM ->
//    far beyond the ~9 KB/CU in flight needed to cover ~900cy HBM latency.
//  - Load issue order == consumption order (per-channel 5-load groups),
//    so s_waitcnt vmcnt(N) retires incrementally during compute.
//  - Correctness scheme unchanged from R2: tap columns clamped to [0,W)
//    (always-legal addresses); out-of-image taps get zero WEIGHT
//    (channel-invariant), so clamped garbage reads contribute nothing.

#define NB 4
#define NC 16
#define NH 512
#define NW 960
#define TH 128
#define TW 240
#define HW (NH * NW)

__global__ __launch_bounds__(320, 4) void tile_warp_kernel(
    const float* __restrict__ tp,   // [B,3,128,240]
    const float* __restrict__ fl,   // [B,16,512,960]
    const float* __restrict__ fr,   // [B,16,512,960]
    float* __restrict__ out)        // [B,48,128,240]
{
    const int u = blockIdx.x * 320 + threadIdx.x;  // column 0..959
    const int Y = blockIdx.y;                      // full-res row 0..511
    const int b = blockIdx.z;                      // batch 0..3
    const int y = Y >> 2, i = Y & 3;
    const int T = u >> 2, j = u & 3;

    const float* frrow = fr + (size_t)(b * NC) * HW + (size_t)Y * NW;
    const float* flrow = fl + (size_t)(b * NC) * HW + (size_t)Y * NW + u;

    // ---- per-thread setup (identical arithmetic to R1/R2) ----
    const int tpb = (b * 3 * TH + y) * TW + T;
    const float d   = tp[tpb];
    const float dxv = tp[tpb + TH * TW];
    const float dyv = tp[tpb + 2 * TH * TW];
    const float base = d + ((float)i - 1.5f) * dyv + ((float)j - 1.5f) * dxv;
    const float xf  = (float)u - base;             // kk=1 (disp_d = 0)
    const float x0f = floorf(xf);
    const float w1  = xf - x0f;
    const float w0  = 1.0f - w1;
    const int   x0  = (int)x0f;
    const int   p   = x0 - 1;                      // taps at x = p .. p+3

    // per-variant masked weights: wv_kk = m[2-kk]*w0k[kk] + m[3-kk]*w1k[kk]
    float w0k[3], w1k[3];
#pragma unroll
    for (int kk = 0; kk < 3; ++kk) {
        const int xa = p + 2 - kk;                 // g0 tap
        const int xb = p + 3 - kk;                 // g1 tap
        w0k[kk] = (xa >= 0 && xa < NW) ? w0 : 0.0f;
        w1k[kk] = (xb >= 0 && xb < NW) ? w1 : 0.0f;
    }

    // clamped tap columns: always-legal addresses; OOB taps have zero weight
    const int i0 = min(max(p    , 0), NW - 1);
    const int i1 = min(max(p + 1, 0), NW - 1);
    const int i2 = min(max(p + 2, 0), NW - 1);
    const int i3 = min(max(p + 3, 0), NW - 1);

    // ---- phase 1: issue ALL loads into registers (static indexing) ----
    float m0[NC], m1[NC], m2[NC], m3[NC], flv[NC];
#pragma unroll
    for (int c = 0; c < NC; ++c) {
        const float* frc = frrow + (size_t)c * HW;
        m0[c]  = frc[i0];
        m1[c]  = frc[i1];
        m2[c]  = frc[i2];
        m3[c]  = frc[i3];
        flv[c] = flrow[(size_t)c * HW];
    }

    // ---- phase 2: compute (waitcnt retires in issue order) ----
    float acc0 = 0.f, acc1 = 0.f, acc2 = 0.f;
#pragma unroll
    for (int c = 0; c < NC; ++c) {
        const float wv0 = m2[c] * w0k[0] + m3[c] * w1k[0];
        const float wv1 = m1[c] * w0k[1] + m2[c] * w1k[1];
        const float wv2 = m0[c] * w0k[2] + m1[c] * w1k[2];
        acc0 += fabsf(flv[c] - wv0);
        acc1 += fabsf(flv[c] - wv1);
        acc2 += fabsf(flv[c] - wv2);
    }

    // ---- store: ch = kk*16 + i*4 + j ----
    const size_t obase = ((size_t)(b * 48 + i * 4 + j) * TH + y) * TW + T;
    out[obase]                        = acc0;
    out[obase + 16 * (size_t)TH * TW] = acc1;
    out[obase + 32 * (size_t)TH * TW] = acc2;
}

extern "C" void kernel_launch(void* const* d_in, const int* in_sizes, int n_in,
                              void* d_out, int out_size, void* d_ws, size_t ws_size,
                              hipStream_t stream) {
    const float* tp = (const float*)d_in[0];
    const float* fl = (const float*)d_in[1];
    const float* fr = (const float*)d_in[2];
    float* out = (float*)d_out;

    dim3 grid(3, NH, NB);   // 3 segments x 512 rows x 4 batches
    dim3 block(320);        // 5 waves, thread -> one output pixel column
    tile_warp_kernel<<<grid, block, 0, stream>>>(tp, fl, fr, out);
}

// Round 3
// 298.333 us; speedup vs baseline: 1.0143x; 1.0143x over previous
//
#include <hip/hip_runtime.h>

// TileWarping: B=4, C=16, H=512, W=960, UP=4 -> out [4, 48, 128, 240] f32.
// R4 design: barrier-free direct gather + COMPILER-ENFORCED load batching.
//  - R3 post-mortem: the source-level "issue all 80 loads, then compute"
//    split was undone by the machine scheduler (VGPR_Count stayed 36 ->
//    ~6 loads in flight -> 16 serialized ~2000cy latency round-trips per
//    wave -> 128us with every throughput counter <20%).
//  - R4: __builtin_amdgcn_sched_barrier(0) between the load phase and the
//    compute phase. Mask 0 = nothing crosses; loads cannot be sunk below
//    it. All 85 VMEM ops go in flight before the first consumption, so a
//    wave pays ~1 latency round-trip instead of 16. VGPR cap 128 via
//    __launch_bounds__(320, 4) holds the 80 loaded floats + addresses.
//  - Issue order == consumption order (per-channel 5-load groups), so the
//    compute phase's s_waitcnt vmcnt(N) retires incrementally.
//  - Correctness scheme unchanged: tap columns clamped to [0,W) (always
//    legal addresses); out-of-image taps get zero WEIGHT (channel-
//    invariant), so clamped garbage reads contribute nothing.

#define NB 4
#define NC 16
#define NH 512
#define NW 960
#define TH 128
#define TW 240
#define HW (NH * NW)

__global__ __launch_bounds__(320, 4) void tile_warp_kernel(
    const float* __restrict__ tp,   // [B,3,128,240]
    const float* __restrict__ fl,   // [B,16,512,960]
    const float* __restrict__ fr,   // [B,16,512,960]
    float* __restrict__ out)        // [B,48,128,240]
{
    const int u = blockIdx.x * 320 + threadIdx.x;  // column 0..959
    const int Y = blockIdx.y;                      // full-res row 0..511
    const int b = blockIdx.z;                      // batch 0..3
    const int y = Y >> 2, i = Y & 3;
    const int T = u >> 2, j = u & 3;

    const float* frrow = fr + (size_t)(b * NC) * HW + (size_t)Y * NW;
    const float* flrow = fl + (size_t)(b * NC) * HW + (size_t)Y * NW + u;

    // ---- per-thread setup (identical arithmetic to R1..R3) ----
    const int tpb = (b * 3 * TH + y) * TW + T;
    const float d   = tp[tpb];
    const float dxv = tp[tpb + TH * TW];
    const float dyv = tp[tpb + 2 * TH * TW];
    const float base = d + ((float)i - 1.5f) * dyv + ((float)j - 1.5f) * dxv;
    const float xf  = (float)u - base;             // kk=1 (disp_d = 0)
    const float x0f = floorf(xf);
    const float w1  = xf - x0f;
    const float w0  = 1.0f - w1;
    const int   x0  = (int)x0f;
    const int   p   = x0 - 1;                      // taps at x = p .. p+3

    // per-variant masked weights: wv_kk = m[2-kk]*w0k[kk] + m[3-kk]*w1k[kk]
    float w0k[3], w1k[3];
#pragma unroll
    for (int kk = 0; kk < 3; ++kk) {
        const int xa = p + 2 - kk;                 // g0 tap
        const int xb = p + 3 - kk;                 // g1 tap
        w0k[kk] = (xa >= 0 && xa < NW) ? w0 : 0.0f;
        w1k[kk] = (xb >= 0 && xb < NW) ? w1 : 0.0f;
    }

    // clamped tap columns: always-legal addresses; OOB taps have zero weight
    const int i0 = min(max(p    , 0), NW - 1);
    const int i1 = min(max(p + 1, 0), NW - 1);
    const int i2 = min(max(p + 2, 0), NW - 1);
    const int i3 = min(max(p + 3, 0), NW - 1);

    // ---- phase 1: issue ALL loads into registers (static indexing) ----
    float m0[NC], m1[NC], m2[NC], m3[NC], flv[NC];
#pragma unroll
    for (int c = 0; c < NC; ++c) {
        const float* frc = frrow + (size_t)c * HW;
        m0[c]  = frc[i0];
        m1[c]  = frc[i1];
        m2[c]  = frc[i2];
        m3[c]  = frc[i3];
        flv[c] = flrow[(size_t)c * HW];
    }

    // Fence: the machine scheduler may not move ANY instruction across this
    // point -> the 80 loads above stay issued before the first use below.
    __builtin_amdgcn_sched_barrier(0);

    // ---- phase 2: compute (waitcnt retires in issue order) ----
    float acc0 = 0.f, acc1 = 0.f, acc2 = 0.f;
#pragma unroll
    for (int c = 0; c < NC; ++c) {
        const float wv0 = m2[c] * w0k[0] + m3[c] * w1k[0];
        const float wv1 = m1[c] * w0k[1] + m2[c] * w1k[1];
        const float wv2 = m0[c] * w0k[2] + m1[c] * w1k[2];
        acc0 += fabsf(flv[c] - wv0);
        acc1 += fabsf(flv[c] - wv1);
        acc2 += fabsf(flv[c] - wv2);
    }

    // ---- store: ch = kk*16 + i*4 + j ----
    const size_t obase = ((size_t)(b * 48 + i * 4 + j) * TH + y) * TW + T;
    out[obase]                        = acc0;
    out[obase + 16 * (size_t)TH * TW] = acc1;
    out[obase + 32 * (size_t)TH * TW] = acc2;
}

extern "C" void kernel_launch(void* const* d_in, const int* in_sizes, int n_in,
                              void* d_out, int out_size, void* d_ws, size_t ws_size,
                              hipStream_t stream) {
    const float* tp = (const float*)d_in[0];
    const float* fl = (const float*)d_in[1];
    const float* fr = (const float*)d_in[2];
    float* out = (float*)d_out;

    dim3 grid(3, NH, NB);   // 3 segments x 512 rows x 4 batches
    dim3 block(320);        // 5 waves, thread -> one output pixel column
    tile_warp_kernel<<<grid, block, 0, stream>>>(tp, fl, fr, out);
}